// Round 9
// baseline (240.887 us; speedup 1.0000x reference)
//
#include <hip/hip_runtime.h>
#include <math.h>

typedef unsigned short u16;
typedef float floatx4 __attribute__((ext_vector_type(4)));
typedef __bf16 bf16x8 __attribute__((ext_vector_type(8)));
typedef u16 u16x4 __attribute__((ext_vector_type(4)));

#define BB 2
#define SS 2048
#define HH 1024
#define NHEAD 16

// fp32 -> bf16 RNE (manual, used in cvt kernel)
__device__ __forceinline__ u16 f2bf(float f) {
  union { float f; unsigned u; } a; a.f = f;
  unsigned r = a.u + 0x7fffu + ((a.u >> 16) & 1u);
  return (u16)(r >> 16);
}

// fp32 -> bf16 via HW cvt (hot paths)
__device__ __forceinline__ u16 bfbits(float f) {
  union { __bf16 h; u16 u; } c; c.h = (__bf16)f; return c.u;
}

// async global->LDS, 16B per lane; LDS dest must be wave-uniform base + lane*16
__device__ __forceinline__ void gload16(const u16* g, u16* l) {
  __builtin_amdgcn_global_load_lds((const __attribute__((address_space(1))) void*)g,
                                   (__attribute__((address_space(3))) void*)l, 16, 0, 0);
}

// ---------------------------------------------------------------------------
// fp32 -> bf16 conversion of pre_out (4M) + 4 weights (1M each) + mask->bias2
// bias2 = (1-mask) * -10000 * log2(e)  (exp2-domain mask bias)
// ---------------------------------------------------------------------------
__global__ __launch_bounds__(256) void cvt_all(
    const float* __restrict__ X, const float* __restrict__ Wq, const float* __restrict__ Wk,
    const float* __restrict__ Wv, const float* __restrict__ Wo, const float* __restrict__ mask,
    u16* __restrict__ Xb, u16* __restrict__ Wqb, u16* __restrict__ Wkb,
    u16* __restrict__ Wvb, u16* __restrict__ Wob, float* __restrict__ B2) {
  int i = blockIdx.x * 256 + threadIdx.x;   // each thread: 4 elements
  if (i >= (2 << 20)) {                     // mask -> bias2 (4096 floats)
    int off = i - (2 << 20);
    float4 m = ((const float4*)mask)[off];
    float4 o;
    o.x = (1.0f - m.x) * (-10000.0f * 1.44269504f);
    o.y = (1.0f - m.y) * (-10000.0f * 1.44269504f);
    o.z = (1.0f - m.z) * (-10000.0f * 1.44269504f);
    o.w = (1.0f - m.w) * (-10000.0f * 1.44269504f);
    ((float4*)B2)[off] = o;
    return;
  }
  const float* src; u16* dst; int off;
  if (i < (1 << 20)) { src = X; dst = Xb; off = i; }
  else {
    int j = i - (1 << 20);
    int m = j >> 18; off = j & ((1 << 18) - 1);
    src = (m == 0) ? Wq : (m == 1) ? Wk : (m == 2) ? Wv : Wo;
    dst = (m == 0) ? Wqb : (m == 1) ? Wkb : (m == 2) ? Wvb : Wob;
  }
  float4 v = ((const float4*)src)[off];
  u16x4 p; p.x = f2bf(v.x); p.y = f2bf(v.y); p.z = f2bf(v.z); p.w = f2bf(v.w);
  ((u16x4*)dst)[off] = p;
}

// ---------------------------------------------------------------------------
// Fused QKV GEMM: 128x128 tile, BK=64 (16 barrier-pairs), 4 waves, 4x4 MFMAs
// per k-slice (2 slices of K=32 per iter).
// LDS rows: 64 u16 = 8 chunks of 16B, 3-bit XOR swizzle pc = lc ^ (r&7).
// mat 0/1 -> Q,K bf16 [s][feature]; mat 2 -> V bf16 transposed [b,h,d,s].
// ---------------------------------------------------------------------------
__global__ __launch_bounds__(256) void qkv_gemm(
    const u16* __restrict__ X,
    const u16* __restrict__ Wq, const u16* __restrict__ Wk, const u16* __restrict__ Wv,
    const float* __restrict__ bq, const float* __restrict__ bk, const float* __restrict__ bv,
    u16* __restrict__ Qo, u16* __restrict__ Ko, u16* __restrict__ Vt) {
  __shared__ u16 As[128 * 64];
  __shared__ u16 Ws[128 * 64];

  const int tid = threadIdx.x;
  const int w = tid >> 6, lane = tid & 63, quad = lane >> 4, l15 = lane & 15;
  const int mat = blockIdx.x >> 3;
  const int col0 = (blockIdx.x & 7) * 128;
  const int row0 = blockIdx.y * 128;
  const u16* W = (mat == 0) ? Wq : (mat == 1) ? Wk : Wv;
  const float* bias = (mat == 0) ? bq : (mat == 1) ? bk : bv;

  const int wm = (w >> 1) * 64, wn = (w & 1) * 64;
  const int sw = l15 & 7;

  floatx4 acc[4][4];
#pragma unroll
  for (int i = 0; i < 4; i++)
#pragma unroll
    for (int j = 0; j < 4; j++) acc[i][j] = {0.f, 0.f, 0.f, 0.f};

  for (int k0 = 0; k0 < HH; k0 += 64) {
    __syncthreads();
#pragma unroll
    for (int i = 0; i < 4; i++) {
      const int c = tid + i * 256;            // 1024 chunks per matrix
      const int r = c >> 3;                   // row 0..127
      const int pc = (c & 7) ^ (r & 7);       // swizzled source chunk
      gload16(X + (row0 + r) * HH + k0 + pc * 8, As + c * 8);
      gload16(W + (col0 + r) * HH + k0 + pc * 8, Ws + c * 8);
    }
    __syncthreads();

#pragma unroll
    for (int s = 0; s < 2; s++) {             // two K=32 slices
      bf16x8 af[4], bfr[4];
#pragma unroll
      for (int i = 0; i < 4; i++)
        af[i] = *(const bf16x8*)(As + (wm + i * 16 + l15) * 64 + (((s * 4 + quad) ^ sw) * 8));
#pragma unroll
      for (int j = 0; j < 4; j++)
        bfr[j] = *(const bf16x8*)(Ws + (wn + j * 16 + l15) * 64 + (((s * 4 + quad) ^ sw) * 8));
#pragma unroll
      for (int i = 0; i < 4; i++)
#pragma unroll
        for (int j = 0; j < 4; j++)
          acc[i][j] = __builtin_amdgcn_mfma_f32_16x16x32_bf16(af[i], bfr[j], acc[i][j], 0, 0, 0);
    }
  }

  const int rb = row0 + wm + quad * 4;
  if (mat < 2) {
    u16* O = (mat == 0) ? Qo : Ko;
#pragma unroll
    for (int j = 0; j < 4; j++) {
      const int col = col0 + wn + j * 16 + l15;
      const float bj = bias[col];
#pragma unroll
      for (int i = 0; i < 4; i++) {
        const int r0 = rb + i * 16;
#pragma unroll
        for (int r = 0; r < 4; r++)
          O[(r0 + r) * HH + col] = bfbits(acc[i][j][r] + bj);
      }
    }
  } else {
#pragma unroll
    for (int j = 0; j < 4; j++) {
      const int col = col0 + wn + j * 16 + l15;
      const float bj = bias[col];
      const int h = col >> 6, d = col & 63;
#pragma unroll
      for (int i = 0; i < 4; i++) {
        const int m0 = rb + i * 16;
        const int b = m0 >> 11, s = m0 & 2047;
        u16x4 pk;
#pragma unroll
        for (int r = 0; r < 4; r++) pk[r] = bfbits(acc[i][j][r] + bj);
        *(u16x4*)(Vt + (((b * NHEAD + h) * 64 + d) * SS + s)) = pk;
      }
    }
  }
}

// ---------------------------------------------------------------------------
// Output projection GEMM: Y[4096,1024] fp32 = Ab @ Wo^T + bo
// 128x64 tiles (grid 16x32 = 512 blocks); 4 waves of 2x4 MFMAs. (r8 version)
// ---------------------------------------------------------------------------
__global__ __launch_bounds__(256) void oproj_gemm(
    const u16* __restrict__ A, const u16* __restrict__ W,
    const float* __restrict__ bias, float* __restrict__ Y) {
  __shared__ u16 As[128 * 32];
  __shared__ u16 Ws[64 * 32];

  const int tid = threadIdx.x;
  const int w = tid >> 6, lane = tid & 63, quad = lane >> 4, l15 = lane & 15;
  const int col0 = blockIdx.x * 64;
  const int row0 = blockIdx.y * 128;

  const int c0 = tid, c1 = tid + 256;
  const int ar0 = c0 >> 2, al0 = ((c0 & 3) ^ (ar0 & 3)) * 8;
  const int ar1 = c1 >> 2, al1 = ((c1 & 3) ^ (ar1 & 3)) * 8;
  const u16* gA0 = A + (row0 + ar0) * HH + al0;
  const u16* gA1 = A + (row0 + ar1) * HH + al1;
  const u16* gW0 = W + (col0 + ar0) * HH + al0;   // 64 rows: ar0 in 0..63
  u16* lA0 = As + c0 * 8; u16* lA1 = As + c1 * 8;
  u16* lW0 = Ws + c0 * 8;

  const int wm = w * 32;
  const int sw = quad ^ (l15 & 3);
  const int aoff = (wm + l15) * 32 + sw * 8;
  const int boff = l15 * 32 + sw * 8;

  floatx4 acc[2][4];
#pragma unroll
  for (int i = 0; i < 2; i++)
#pragma unroll
    for (int j = 0; j < 4; j++) acc[i][j] = {0.f, 0.f, 0.f, 0.f};

  for (int k0 = 0; k0 < HH; k0 += 32) {
    __syncthreads();
    gload16(gA0 + k0, lA0);
    gload16(gA1 + k0, lA1);
    if (tid < 256) gload16(gW0 + k0, lW0);
    __syncthreads();
    bf16x8 af[2], bfr[4];
#pragma unroll
    for (int i = 0; i < 2; i++) af[i] = *(const bf16x8*)(As + aoff + i * 512);
#pragma unroll
    for (int j = 0; j < 4; j++) bfr[j] = *(const bf16x8*)(Ws + boff + j * 512);
#pragma unroll
    for (int i = 0; i < 2; i++)
#pragma unroll
      for (int j = 0; j < 4; j++)
        acc[i][j] = __builtin_amdgcn_mfma_f32_16x16x32_bf16(af[i], bfr[j], acc[i][j], 0, 0, 0);
  }

  const int rb = row0 + wm + quad * 4;
#pragma unroll
  for (int j = 0; j < 4; j++) {
    const int col = col0 + j * 16 + l15;
    const float bj = bias[col];
#pragma unroll
    for (int i = 0; i < 2; i++) {
      const int r0 = rb + i * 16;
#pragma unroll
      for (int r = 0; r < 4; r++)
        Y[(r0 + r) * HH + col] = acc[i][j][r] + bj;
    }
  }
}

// ---------------------------------------------------------------------------
// MFMA flash attention, no-max exp2 softmax, 128-key staged tiles:
// 16 barrier-pairs (vs 32), each staging K[128 keys][64] + Vt[64][128 keys],
// then TWO 64-key compute sub-rounds (P buffer is wave-private -> no barrier
// between sub-rounds). Grid (16 qtiles of 128 rows, 32 bh); wave owns 32 rows.
// ---------------------------------------------------------------------------
#define QT 128

__global__ __launch_bounds__(256, 3) void attn_mfma(
    const u16* __restrict__ Q, const u16* __restrict__ K, const u16* __restrict__ Vt,
    const float* __restrict__ B2, u16* __restrict__ O) {
  __shared__ u16 UQ[9216];        // Q [128][64] (8192) ∪ P (wave w at w*2304, [32][72])
  __shared__ u16 Ks[128 * 64];    // 16 KB: 128 key-rows x 64 d
  __shared__ u16 Vs[64 * 128];    // 16 KB: 64 d-rows x 128 keys

  const int qt = blockIdx.x, bh = blockIdx.y;
  const int b = bh >> 4, h = bh & 15;
  const int tid = threadIdx.x;
  const int w = tid >> 6, lane = tid & 63, quad = lane >> 4, l15 = lane & 15;
  const int sw = l15 & 7;

  const int qbase  = (b * SS + qt * QT) * HH + h * 64;
  const int kvbase = (b * SS) * HH + h * 64;
  const int vtbase = (b * NHEAD + h) * 64 * SS;

  // stage Q tile: 128 rows x 8 chunks, swizzle pc = lc ^ (r&7)
#pragma unroll
  for (int i = 0; i < 4; i++) {
    const int c = tid + i * 256;
    const int r = c >> 3, pc = (c & 7) ^ (r & 7);
    gload16(Q + qbase + r * HH + pc * 8, UQ + c * 8);
  }
  __syncthreads();

  // hoist Q fragments (2 m-tiles x 2 k-halves) into registers
  bf16x8 aQ[2][2];
#pragma unroll
  for (int mt = 0; mt < 2; mt++) {
    const u16* qr = UQ + (w * 32 + mt * 16 + l15) * 64;
    aQ[mt][0] = *(const bf16x8*)(qr + ((quad ^ sw) * 8));
    aQ[mt][1] = *(const bf16x8*)(qr + (((4 + quad) ^ sw) * 8));
  }

  floatx4 o[2][4];
  float lp[2][4];
#pragma unroll
  for (int mt = 0; mt < 2; mt++)
#pragma unroll
    for (int j = 0; j < 4; j++) o[mt][j] = {0.f, 0.f, 0.f, 0.f};
#pragma unroll
  for (int mt = 0; mt < 2; mt++)
#pragma unroll
    for (int r = 0; r < 4; r++) lp[mt][r] = 0.f;

  u16* Pw = UQ + w * 2304;
  const float* B2row = B2 + b * SS;

  for (int it = 0; it < 16; it++) {
    __syncthreads();   // all waves done reading Ks/Vs (it 0: done hoisting Q)
    // stage K: 1024 chunks, key-row r = c>>3 (0..127), pc = lc ^ (r&7)
    // stage V: 1024 chunks, d-row   r = c>>4 (0..63), 16 chunks/row, pc = lc ^ (r&15)
#pragma unroll
    for (int i = 0; i < 4; i++) {
      const int c = tid + i * 256;
      const int kr = c >> 3, kpc = (c & 7) ^ (kr & 7);
      gload16(K + kvbase + (it * 128 + kr) * HH + kpc * 8, Ks + c * 8);
      const int vr = c >> 4, vpc = (c & 15) ^ (vr & 15);
      gload16(Vt + vtbase + vr * SS + it * 128 + vpc * 8, Vs + c * 8);
    }
    __syncthreads();

#pragma unroll
    for (int kt2 = 0; kt2 < 2; kt2++) {
      // QK^T over this sub-round's 64 keys
      floatx4 s[2][4];
#pragma unroll
      for (int j = 0; j < 4; j++) {
        const u16* kr = Ks + (kt2 * 64 + j * 16 + l15) * 64;
        bf16x8 b0 = *(const bf16x8*)(kr + ((quad ^ sw) * 8));
        bf16x8 b1 = *(const bf16x8*)(kr + (((4 + quad) ^ sw) * 8));
#pragma unroll
        for (int mt = 0; mt < 2; mt++) {
          floatx4 z = {0.f, 0.f, 0.f, 0.f};
          z = __builtin_amdgcn_mfma_f32_16x16x32_bf16(aQ[mt][0], b0, z, 0, 0, 0);
          s[mt][j] = __builtin_amdgcn_mfma_f32_16x16x32_bf16(aQ[mt][1], b1, z, 0, 0, 0);
        }
      }

      // p = 2^(s * 0.125*log2e + bias2); accumulate per-lane l partials
#pragma unroll
      for (int j = 0; j < 4; j++) {
        const float bb = B2row[it * 128 + kt2 * 64 + j * 16 + l15];
#pragma unroll
        for (int mt = 0; mt < 2; mt++)
#pragma unroll
          for (int r = 0; r < 4; r++) {
            const float p = __builtin_amdgcn_exp2f(s[mt][j][r] * 0.180336880f + bb);
            s[mt][j][r] = p;
            lp[mt][r] += p;
          }
      }

      // P -> LDS (C-layout rows mt*16+quad*4+r, stride 72; wave-private)
#pragma unroll
      for (int mt = 0; mt < 2; mt++)
#pragma unroll
        for (int j = 0; j < 4; j++)
#pragma unroll
          for (int r = 0; r < 4; r++)
            Pw[(mt * 16 + quad * 4 + r) * 72 + j * 16 + l15] = bfbits(s[mt][j][r]);

      // PV (same-wave LDS RAW: ordered by lgkmcnt)
      bf16x8 pa[2][2];
#pragma unroll
      for (int mt = 0; mt < 2; mt++) {
        const u16* pr = Pw + (mt * 16 + l15) * 72;
        pa[mt][0] = *(const bf16x8*)(pr + quad * 8);
        pa[mt][1] = *(const bf16x8*)(pr + 32 + quad * 8);
      }
#pragma unroll
      for (int j = 0; j < 4; j++) {
        const u16* vr = Vs + (j * 16 + l15) * 128;   // d-row, 128-key stride
        bf16x8 v0 = *(const bf16x8*)(vr + (((kt2 * 8 + quad) ^ l15) * 8));
        bf16x8 v1 = *(const bf16x8*)(vr + (((kt2 * 8 + 4 + quad) ^ l15) * 8));
#pragma unroll
        for (int mt = 0; mt < 2; mt++) {
          o[mt][j] = __builtin_amdgcn_mfma_f32_16x16x32_bf16(pa[mt][0], v0, o[mt][j], 0, 0, 0);
          o[mt][j] = __builtin_amdgcn_mfma_f32_16x16x32_bf16(pa[mt][1], v1, o[mt][j], 0, 0, 0);
        }
      }
    }
  }

  // final l reduction across the 16 lanes holding each row
#pragma unroll
  for (int mt = 0; mt < 2; mt++)
#pragma unroll
    for (int r = 0; r < 4; r++) {
      float v = lp[mt][r];
      v += __shfl_xor(v, 1); v += __shfl_xor(v, 2);
      v += __shfl_xor(v, 4); v += __shfl_xor(v, 8);
      lp[mt][r] = v;
    }

#pragma unroll
  for (int mt = 0; mt < 2; mt++) {
    const int orow0 = b * SS + qt * QT + w * 32 + mt * 16 + quad * 4;
#pragma unroll
    for (int r = 0; r < 4; r++) {
      const float inv = 1.0f / lp[mt][r];
#pragma unroll
      for (int j = 0; j < 4; j++)
        O[(orow0 + r) * HH + h * 64 + j * 16 + l15] = bfbits(o[mt][j][r] * inv);
    }
  }
}

// ---------------------------------------------------------------------------
// out = LayerNorm(x0 + y) * w + b
// ---------------------------------------------------------------------------
__device__ __forceinline__ float block_sum256(float v) {
  __shared__ float sb[4];
#pragma unroll
  for (int o = 1; o < 64; o <<= 1) v += __shfl_xor(v, o);
  if ((threadIdx.x & 63) == 0) sb[threadIdx.x >> 6] = v;
  __syncthreads();
  float r = sb[0] + sb[1] + sb[2] + sb[3];
  __syncthreads();
  return r;
}

__global__ __launch_bounds__(256) void add_layernorm(
    const float* __restrict__ x0, const float* __restrict__ y,
    const float* __restrict__ w, const float* __restrict__ b,
    float* __restrict__ out) {
  const int row = blockIdx.x;
  const int t = threadIdx.x;
  const float* xr = x0 + (size_t)row * HH;
  const float* yr = y + (size_t)row * HH;

  float v[4];
  float sum = 0.f;
#pragma unroll
  for (int i = 0; i < 4; i++) {
    int idx = t + i * 256;
    v[i] = xr[idx] + yr[idx];
    sum += v[i];
  }
  float mean = block_sum256(sum) * (1.0f / HH);

  float sq = 0.f;
#pragma unroll
  for (int i = 0; i < 4; i++) {
    float d = v[i] - mean;
    sq += d * d;
  }
  float var = block_sum256(sq) * (1.0f / HH);
  float inv = rsqrtf(var + 1e-12f);

#pragma unroll
  for (int i = 0; i < 4; i++) {
    int idx = t + i * 256;
    out[(size_t)row * HH + idx] = w[idx] * ((v[i] - mean) * inv) + b[idx];
  }
}

// ---------------------------------------------------------------------------
extern "C" void kernel_launch(void* const* d_in, const int* in_sizes, int n_in,
                              void* d_out, int out_size, void* d_ws, size_t ws_size,
                              hipStream_t stream) {
  const float* pre_out = (const float*)d_in[0];
  const float* mask    = (const float*)d_in[1];
  const float* Wq = (const float*)d_in[2];
  const float* bq = (const float*)d_in[3];
  const float* Wk = (const float*)d_in[4];
  const float* bk = (const float*)d_in[5];
  const float* Wv = (const float*)d_in[6];
  const float* bv = (const float*)d_in[7];
  const float* Wo = (const float*)d_in[8];
  const float* bo = (const float*)d_in[9];
  const float* ln_w = (const float*)d_in[10];
  const float* ln_b = (const float*)d_in[11];
  float* out = (float*)d_out;

  // workspace layout
  u16* Xb  = (u16*)d_ws;                // 4M u16
  u16* Wqb = Xb + (4 << 20);            // 1M
  u16* Wkb = Wqb + (1 << 20);
  u16* Wvb = Wkb + (1 << 20);
  u16* Wob = Wvb + (1 << 20);
  u16* Qb  = Wob + (1 << 20);           // 4M
  u16* Kb  = Qb + (4 << 20);            // 4M
  u16* Vtb = Kb + (4 << 20);            // 4M
  u16* Ab  = Vtb + (4 << 20);           // 4M
  float* Yb = (float*)(Ab + (4 << 20)); // 4M fp32
  float* B2 = Yb + (4 << 20);           // 4096 fp32 (mask bias, exp2 domain)

  cvt_all<<<8196, 256, 0, stream>>>(pre_out, Wq, Wk, Wv, Wo, mask,
                                    Xb, Wqb, Wkb, Wvb, Wob, B2);

  qkv_gemm<<<dim3(24, 32), 256, 0, stream>>>(Xb, Wqb, Wkb, Wvb, bq, bk, bv, Qb, Kb, Vtb);

  attn_mfma<<<dim3(SS / QT, BB * NHEAD), 256, 0, stream>>>(Qb, Kb, Vtb, B2, Ab);

  oproj_gemm<<<dim3(16, 32), 256, 0, stream>>>(Ab, Wob, bo, Yb);

  add_layernorm<<<BB * SS, 256, 0, stream>>>(pre_out, Yb, ln_w, ln_b, out);
}